// Round 13
// baseline (356.978 us; speedup 1.0000x reference)
//
#include <hip/hip_runtime.h>
#include <math.h>

#define EPSV 1e-5f

typedef __attribute__((ext_vector_type(8)))  short short8_t;
typedef __attribute__((ext_vector_type(4)))  unsigned uint4_t;
typedef __attribute__((ext_vector_type(16))) float f32x16;

static __device__ __forceinline__ short f2bf(float f) {
    union { float f; unsigned u; } v; v.f = f;
    unsigned r = (v.u + 0x7FFFu + ((v.u >> 16) & 1u)) >> 16;
    return (short)r;
}
static __device__ __forceinline__ unsigned pack2bf(float a, float b) {
    return (unsigned)(unsigned short)f2bf(a) | ((unsigned)(unsigned short)f2bf(b) << 16);
}
static __device__ __forceinline__ float bflo(unsigned u) {
    union { unsigned u; float f; } t; t.u = u << 16; return t.f;
}
static __device__ __forceinline__ float bfhi(unsigned u) {
    union { unsigned u; float f; } t; t.u = u & 0xffff0000u; return t.f;
}

// ---------------- prep_all: A2 | A1 | Aup | k0-transpose in ONE launch -----------
// Blocks   0..287  : w_reg -> A2
// Blocks 288..323  : w_off/w_mod -> A1
// Blocks 324..835  : w_up -> Aup
// Blocks 836..2883 : x NCHW -> xT NHWC  (vectorized: float4 loads, ushort4 stores)
__global__ __launch_bounds__(256) void prep_all(
    const float* __restrict__ w_reg, const float* __restrict__ w_off,
    const float* __restrict__ w_mod, const float* __restrict__ w_up,
    const float* __restrict__ x,
    short* __restrict__ A2, short* __restrict__ A1, short* __restrict__ Aup,
    unsigned short* __restrict__ xT) {
    __shared__ unsigned short t[64 * 65];
    int bx  = blockIdx.x;
    int tid = threadIdx.x;

    if (bx < 288) {                       // ---- A2 ----
        int gid = bx * 256 + tid;
        int l  = gid & 63;
        int ot = (gid >> 6) & 7;
        int s  = gid >> 9;
        int o  = ot * 32 + (l & 31);
        int tap = s >> 4;
        int cb  = (s & 15) * 16 + (l >> 5) * 8;
        short* dst = A2 + (size_t)gid * 8;
#pragma unroll
        for (int j = 0; j < 8; ++j)
            dst[j] = f2bf(w_reg[(o * 256 + cb + j) * 9 + tap]);
    } else if (bx < 324) {                // ---- A1 ----
        int gid = (bx - 288) * 256 + tid;
        int l  = gid & 63;
        int s  = gid >> 6;
        int tap = s >> 4;
        int cq  = s & 15;
        int co  = l & 31;
        int cb  = cq * 16 + (l >> 5) * 8;
        short* dst = A1 + (size_t)gid * 8;
#pragma unroll
        for (int j = 0; j < 8; ++j) {
            int c = cb + j;
            float v = 0.f;
            if (co < 18)      v = w_off[(co * 256 + c) * 9 + tap];
            else if (co < 27) v = w_mod[((co - 18) * 256 + c) * 9 + tap];
            dst[j] = f2bf(v);
        }
    } else if (bx < 836) {                // ---- Aup ----
        int gid = (bx - 324) * 256 + tid;
        int l  = gid & 63;
        int ot = (gid >> 6) & 7;
        int s  = (gid >> 9) & 63;
        int sx = (gid >> 15) & 1;
        int sy = (gid >> 16) & 1;
        int chunk = s >> 4;
        int tap = (s >> 2) & 3;
        int ch  = s & 3;
        int ty = tap >> 1, tx = tap & 1;
        int o  = ot * 32 + (l & 31);
        int cb = chunk * 64 + ch * 16 + (l >> 5) * 8;
        int ky = (1 - sy) + 2 * ty;
        int kx = (1 - sx) + 2 * tx;
        short* dst = Aup + (size_t)gid * 8;
#pragma unroll
        for (int j = 0; j < 8; ++j)
            dst[j] = f2bf(w_up[((cb + j) * 256 + o) * 16 + ky * 4 + kx]);
    } else {                              // ---- k0 transpose (vectorized) ----
        int kb  = bx - 836;
        int b   = kb & 7;
        int hwt = (kb >> 3) & 63;
        int ct  = kb >> 9;
        const float* xb = x + ((size_t)b * 256 + ct * 64) * 4096 + hwt * 64;
        // stage: 64 c-rows x 16 hw-quads, float4 per unit (4 its x 256 thr)
#pragma unroll
        for (int it = 0; it < 4; ++it) {
            int e = tid + it * 256;       // 0..1023
            int c = e >> 4;               // 0..63
            int j = e & 15;               // hw-quad
            float4 v = *(const float4*)(xb + (size_t)c * 4096 + 4 * j);
            t[c * 65 + 4 * j + 0] = (unsigned short)f2bf(v.x);
            t[c * 65 + 4 * j + 1] = (unsigned short)f2bf(v.y);
            t[c * 65 + 4 * j + 2] = (unsigned short)f2bf(v.z);
            t[c * 65 + 4 * j + 3] = (unsigned short)f2bf(v.w);
        }
        __syncthreads();
        // write: 64 hw-rows x 16 c-quads, ushort4 per unit (4 its x 256 thr)
        unsigned short* xo = xT + ((size_t)b * 4096 + hwt * 64) * 256 + ct * 64;
#pragma unroll
        for (int it = 0; it < 4; ++it) {
            int e  = tid + it * 256;      // 0..1023
            int hw = e >> 4;              // 0..63
            int q  = e & 15;              // c-quad
            ushort4 w;
            w.x = t[(4 * q + 0) * 65 + hw];
            w.y = t[(4 * q + 1) * 65 + hw];
            w.z = t[(4 * q + 2) * 65 + hw];
            w.w = t[(4 * q + 3) * 65 + hw];
            *(ushort4*)&xo[(size_t)hw * 256 + 4 * q] = w;
        }
    }
}

// ---------------- k1: offset+mask conv via bf16 MFMA -> offmask (round-9 exact) --
__global__ __launch_bounds__(256, 2) void k1_mfma(
    const unsigned short* __restrict__ xT, const short* __restrict__ A1,
    const float* __restrict__ b_off, const float* __restrict__ b_mod,
    float* __restrict__ offmask) {
    __shared__ short xs[3 * 66 * 72];     // 28,512 B
    __shared__ float red[4][32][64];      // 32,768 B

    int bx = blockIdx.x;
    int b  = bx & 7;
    int h  = bx >> 3;
    int tid  = threadIdx.x;
    int lane = tid & 63;
    int wv   = tid >> 6;       // 0..3 (K-split)
    int ln = lane & 31;
    int lh = lane >> 5;

    if (tid < 192) {
        int r    = tid >> 6;
        int rest = tid & 63;
        int colp = (rest >> 5) * 65;
        int cd   = rest & 31;
        ((unsigned*)xs)[((r * 66 + colp) * 72 >> 1) + cd] = 0;
    }

    f32x16 acc[2];
#pragma unroll
    for (int pt = 0; pt < 2; ++pt)
#pragma unroll
        for (int r = 0; r < 16; ++r) acc[pt][r] = 0.f;

    const unsigned short* xTb = xT + (size_t)b * 4096 * 256;

    for (int cc = 0; cc < 256; cc += 64) {
#pragma unroll
        for (int it = 0; it < 6; ++it) {
            int e   = tid + it * 256;
            int ch8 = e & 7;             // 8-c chunk
            int col = (e >> 3) & 63;
            int r   = e >> 9;            // 0..2
            int row = h - 1 + r;
            bool v  = (row >= 0) & (row <= 63);
            short8_t val = {0,0,0,0,0,0,0,0};
            if (v) val = *(const short8_t*)(xTb + ((size_t)row * 64 + col) * 256 + cc + ch8 * 8);
            *(short8_t*)&xs[(r * 66 + col + 1) * 72 + ch8 * 8] = val;
        }
        __syncthreads();

#pragma unroll
        for (int tap = 0; tap < 9; ++tap) {
            int ky = tap / 3, kx = tap - 3 * (tap / 3);
            int s = tap * 16 + (cc >> 4) + wv;
            short8_t afr = *(const short8_t*)(A1 + ((size_t)s * 64 + lane) * 8);
            const short* bp = &xs[(ky * 66 + ln + kx) * 72 + wv * 16 + lh * 8];
            short8_t b0 = *(const short8_t*)bp;
            short8_t b1 = *(const short8_t*)(bp + 32 * 72);
            acc[0] = __builtin_amdgcn_mfma_f32_32x32x16_bf16(afr, b0, acc[0], 0, 0, 0);
            acc[1] = __builtin_amdgcn_mfma_f32_32x32x16_bf16(afr, b1, acc[1], 0, 0, 0);
        }
        __syncthreads();
    }

#pragma unroll
    for (int pt = 0; pt < 2; ++pt)
#pragma unroll
        for (int reg = 0; reg < 16; ++reg) {
            int row = (reg & 3) + 8 * (reg >> 2) + 4 * lh;
            red[wv][row][pt * 32 + ln] = acc[pt][reg];
        }
    __syncthreads();

    int pos = tid & 63;
    int cg  = tid >> 6;
#pragma unroll
    for (int i = 0; i < 7; ++i) {
        int co = 4 * i + cg;
        if (co < 27) {
            float sum = red[0][co][pos] + red[1][co][pos]
                      + red[2][co][pos] + red[3][co][pos];
            if (co < 18) {
                sum += b_off[co];
            } else {
                sum += b_mod[co - 18];
                sum = 2.f / (1.f + expf(-sum));
            }
            offmask[((size_t)(b * 27 + co) << 12) + (h << 6) + pos] = sum;
        }
    }
}

// ---------------- k2: deform sample (dwordx4 gather) + MFMA + bn1+relu -> h1 -----
// Round-9 version EXACTLY (best verified).
__global__ __launch_bounds__(512, 4) void k2_deform(
    const unsigned short* __restrict__ xT, const float* __restrict__ offmask,
    const short* __restrict__ A2,
    const float* __restrict__ g1, const float* __restrict__ be1,
    const float* __restrict__ mu1, const float* __restrict__ va1,
    unsigned short* __restrict__ h1) {
    __shared__ unsigned short lds_v[64 * 264];   // [pos][c], pitch 264
    __shared__ int   sidx[9][64][4];
    __shared__ float swt [9][64][4];

    int bx = blockIdx.x;
    int b  = bx & 7;
    int h  = bx >> 3;
    int tid  = threadIdx.x;
    int lane = tid & 63;
    int wv   = tid >> 6;          // 0..7
    int ln = lane & 31;
    int lh = lane >> 5;

#pragma unroll
    for (int it = 0; it < 2; ++it) {
        int e = it * 512 + tid;
        if (e < 576) {
            int tap = e >> 6;
            int pos = e & 63;
            const float* om = offmask + ((size_t)b * 27 << 12) + (h << 6) + pos;
            float oy = om[(size_t)(2 * tap) << 12];
            float ox = om[(size_t)(2 * tap + 1) << 12];
            float m2 = om[(size_t)(18 + tap) << 12];
            int ky = tap / 3, kx = tap - 3 * (tap / 3);
            float py = (float)(h - 1 + ky) + oy;
            float px = (float)(pos - 1 + kx) + ox;
            float y0f = floorf(py), x0f = floorf(px);
            float wy1 = py - y0f, wy0 = 1.f - wy1;
            float wx1 = px - x0f, wx0 = 1.f - wx1;
            int y0 = (int)y0f, xq = (int)x0f;
            int y1 = y0 + 1, x1 = xq + 1;
            bool vy0 = (y0 >= 0) & (y0 < 64), vy1 = (y1 >= 0) & (y1 < 64);
            bool vx0 = (xq >= 0) & (xq < 64), vx1 = (x1 >= 0) & (x1 < 64);
            int y0c = min(max(y0, 0), 63), y1c = min(max(y1, 0), 63);
            int x0c = min(max(xq, 0), 63), x1c = min(max(x1, 0), 63);
            sidx[tap][pos][0] = y0c * 64 + x0c;  swt[tap][pos][0] = (vy0 && vx0) ? m2 * wy0 * wx0 : 0.f;
            sidx[tap][pos][1] = y0c * 64 + x1c;  swt[tap][pos][1] = (vy0 && vx1) ? m2 * wy0 * wx1 : 0.f;
            sidx[tap][pos][2] = y1c * 64 + x0c;  swt[tap][pos][2] = (vy1 && vx0) ? m2 * wy1 * wx0 : 0.f;
            sidx[tap][pos][3] = y1c * 64 + x1c;  swt[tap][pos][3] = (vy1 && vx1) ? m2 * wy1 * wx1 : 0.f;
        }
    }
    __syncthreads();

    f32x16 acc[2];
#pragma unroll
    for (int pt = 0; pt < 2; ++pt)
#pragma unroll
        for (int r = 0; r < 16; ++r) acc[pt][r] = 0.f;

    const unsigned* xTb = (const unsigned*)(xT + (size_t)b * 4096 * 256);

    for (int k = 0; k < 9; ++k) {
#pragma unroll
        for (int qq = 0; qq < 4; ++qq) {
            int pos = wv * 8 + qq * 2 + lh;      // lanes 0-31: even pos, 32-63: odd
            float a[8];
#pragma unroll
            for (int j = 0; j < 8; ++j) a[j] = 0.f;
#pragma unroll
            for (int i = 0; i < 4; ++i) {
                int   idx = sidx[k][pos][i];
                float wt  = swt[k][pos][i];
                uint4_t u = *(const uint4_t*)(xTb + ((size_t)idx << 7) + (ln << 2));
#pragma unroll
                for (int d = 0; d < 4; ++d) {
                    a[2 * d + 0] = fmaf(wt, bflo(u[d]), a[2 * d + 0]);
                    a[2 * d + 1] = fmaf(wt, bfhi(u[d]), a[2 * d + 1]);
                }
            }
            unsigned* dst = (unsigned*)&lds_v[pos * 264 + ln * 8];
            uint4_t w;
            w[0] = pack2bf(a[0], a[1]);
            w[1] = pack2bf(a[2], a[3]);
            w[2] = pack2bf(a[4], a[5]);
            w[3] = pack2bf(a[6], a[7]);
            *(uint4_t*)dst = w;
        }
        __syncthreads();

#pragma unroll 4
        for (int sl = 0; sl < 16; ++sl) {
            int s = k * 16 + sl;
            short8_t afr = *(const short8_t*)(A2 + (((size_t)s * 8 + wv) * 64 + lane) * 8);
            short8_t b0 = *(const short8_t*)&lds_v[ln        * 264 + sl * 16 + lh * 8];
            short8_t b1 = *(const short8_t*)&lds_v[(32 + ln) * 264 + sl * 16 + lh * 8];
            acc[0] = __builtin_amdgcn_mfma_f32_32x32x16_bf16(afr, b0, acc[0], 0, 0, 0);
            acc[1] = __builtin_amdgcn_mfma_f32_32x32x16_bf16(afr, b1, acc[1], 0, 0, 0);
        }
        __syncthreads();
    }

#pragma unroll
    for (int reg = 0; reg < 16; ++reg) {
        int o = wv * 32 + (reg & 3) + 8 * (reg >> 2) + 4 * lh;
        float sc = g1[o] / sqrtf(va1[o] + EPSV);
        float sh = be1[o] - mu1[o] * sc;
        size_t ob = ((size_t)(b * 256 + o) * 64 + h) * 64;
#pragma unroll
        for (int pt = 0; pt < 2; ++pt) {
            float v = fmaxf(fmaf(acc[pt][reg], sc, sh), 0.f);
            h1[ob + pt * 32 + ln] = (unsigned short)f2bf(v);
        }
    }
}

// ---------------- k3: conv_transpose via bf16 MFMA, 256-thr o-split (round 8) ----
__global__ __launch_bounds__(256, 4) void k3_convt(
    const unsigned short* __restrict__ h1, const short* __restrict__ Aup,
    const float* __restrict__ g2, const float* __restrict__ be2,
    const float* __restrict__ mu2, const float* __restrict__ va2,
    float* __restrict__ out) {
    __shared__ short lds[2 * 66 * 72];   // 19,008 B

    int bx = blockIdx.x;
    int oh = bx & 1;             // o-half
    int b  = (bx >> 1) & 7;
    int y  = bx >> 4;            // 0..127
    int sy = y & 1;
    int m  = y >> 1;
    int tid  = threadIdx.x;      // 0..255
    int lane = tid & 63;
    int wv   = tid >> 6;         // 0..3
    int owh = wv & 1;
    int sx  = wv >> 1;
    int ln = lane & 31;
    int lh = lane >> 5;

    int row0 = m + sy;           // ty=0 source row
    int row1 = row0 - 1;         // ty=1 source row
    bool v0 = (row0 <= 63);
    bool v1 = (row1 >= 0);

#pragma unroll
    for (int e0 = 0; e0 < 2; ++e0) {
        int e = tid + e0 * 256;
        if (e < 288) {
            int r  = e / 144;
            int rm = e - r * 144;
            int cp = (rm / 72) * 65;
            int cz = rm - (rm / 72) * 72;
            lds[(r * 66 + cp) * 72 + cz] = 0;
        }
    }

    f32x16 acc[2][2];            // [i o-tile][mh]
#pragma unroll
    for (int i = 0; i < 2; ++i)
#pragma unroll
        for (int mh = 0; mh < 2; ++mh)
#pragma unroll
            for (int r = 0; r < 16; ++r) acc[i][mh][r] = 0.f;

    const unsigned short* hb = h1 + (size_t)b * 256 * 4096;
    const short* Abase = Aup + (size_t)(sy * 2 + sx) * 262144;
    int col = tid & 63;
    int ug  = tid >> 6;          // 0..3 staging group

    for (int cc = 0; cc < 256; cc += 64) {
#pragma unroll
        for (int it = 0; it < 8; ++it) {
            int idx  = ug + 4 * it;      // 0..31
            int r    = idx >> 4;
            int quad = idx & 15;
            int row  = r ? row1 : row0;
            bool v   = r ? v1 : v0;
            int cb   = cc + quad * 4;
            unsigned short u0 = v ? hb[(size_t)(cb + 0) * 4096 + row * 64 + col] : 0;
            unsigned short u1 = v ? hb[(size_t)(cb + 1) * 4096 + row * 64 + col] : 0;
            unsigned short u2 = v ? hb[(size_t)(cb + 2) * 4096 + row * 64 + col] : 0;
            unsigned short u3 = v ? hb[(size_t)(cb + 3) * 4096 + row * 64 + col] : 0;
            unsigned* dst = (unsigned*)&lds[(r * 66 + col + 1) * 72 + quad * 4];
            dst[0] = (unsigned)u0 | ((unsigned)u1 << 16);
            dst[1] = (unsigned)u2 | ((unsigned)u3 << 16);
        }
        __syncthreads();

#pragma unroll
        for (int st = 0; st < 16; ++st) {
            int tap = st >> 2;
            int ch  = st & 3;
            int ty = tap >> 1, tx = tap & 1;
            int s_g = (cc >> 2) + st;
            const short* ap = Abase + (size_t)s_g * 4096 + lane * 8;
            short8_t a0 = *(const short8_t*)(ap + (size_t)(oh * 4 + owh) * 512);
            short8_t a1 = *(const short8_t*)(ap + (size_t)(oh * 4 + owh + 2) * 512);
            int cbase = ty * 66 + ln + sx - tx + 1;
            short8_t b0 = *(const short8_t*)&lds[cbase * 72 + ch * 16 + lh * 8];
            short8_t b1 = *(const short8_t*)&lds[(cbase + 32) * 72 + ch * 16 + lh * 8];
            acc[0][0] = __builtin_amdgcn_mfma_f32_32x32x16_bf16(a0, b0, acc[0][0], 0, 0, 0);
            acc[0][1] = __builtin_amdgcn_mfma_f32_32x32x16_bf16(a0, b1, acc[0][1], 0, 0, 0);
            acc[1][0] = __builtin_amdgcn_mfma_f32_32x32x16_bf16(a1, b0, acc[1][0], 0, 0, 0);
            acc[1][1] = __builtin_amdgcn_mfma_f32_32x32x16_bf16(a1, b1, acc[1][1], 0, 0, 0);
        }
        __syncthreads();
    }

#pragma unroll
    for (int i = 0; i < 2; ++i) {
#pragma unroll
        for (int reg = 0; reg < 16; ++reg) {
            int o = (oh * 4 + owh + 2 * i) * 32 + (reg & 3) + 8 * (reg >> 2) + 4 * lh;
            float sc = g2[o] / sqrtf(va2[o] + EPSV);
            float sh = be2[o] - mu2[o] * sc;
            size_t ob = ((size_t)(b * 256 + o) * 128 + y) * 128;
#pragma unroll
            for (int mh = 0; mh < 2; ++mh) {
                int x = 2 * (mh * 32 + ln) + sx;
                out[ob + x] = fmaxf(fmaf(acc[i][mh][reg], sc, sh), 0.f);
            }
        }
    }
}

extern "C" void kernel_launch(void* const* d_in, const int* in_sizes, int n_in,
                              void* d_out, int out_size, void* d_ws, size_t ws_size,
                              hipStream_t stream) {
    const float* x      = (const float*)d_in[0];
    const float* w_off  = (const float*)d_in[1];
    const float* b_off  = (const float*)d_in[2];
    const float* w_mod  = (const float*)d_in[3];
    const float* b_mod  = (const float*)d_in[4];
    const float* w_reg  = (const float*)d_in[5];
    const float* g1     = (const float*)d_in[6];
    const float* be1    = (const float*)d_in[7];
    const float* mu1    = (const float*)d_in[8];
    const float* va1    = (const float*)d_in[9];
    const float* w_up   = (const float*)d_in[10];
    const float* g2     = (const float*)d_in[11];
    const float* be2    = (const float*)d_in[12];
    const float* mu2    = (const float*)d_in[13];
    const float* va2    = (const float*)d_in[14];

    float* ws      = (float*)d_ws;
    float* offmask = ws;                                     //   884,736 f
    short* A2      = (short*)(offmask + 884736);             //   589,824 sh
    short* A1      = A2 + 589824;                            //    73,728 sh
    short* Aup     = A1 + 73728;                             // 1,048,576 sh
    unsigned short* h1 = (unsigned short*)(Aup + 1048576);   // 8,388,608 sh
    unsigned short* xT = h1 + 8388608;                       // 8,388,608 sh

    prep_all  <<<2884, 256, 0, stream>>>(w_reg, w_off, w_mod, w_up, x,
                                         A2, A1, Aup, xT);
    k1_mfma   <<<512,  256, 0, stream>>>(xT, A1, b_off, b_mod, offmask);
    k2_deform <<<512,  512, 0, stream>>>(xT, offmask, A2, g1, be1, mu1, va1, h1);
    k3_convt  <<<2048, 256, 0, stream>>>(h1, Aup, g2, be2, mu2, va2, (float*)d_out);
}

// Round 14
// 354.815 us; speedup vs baseline: 1.0061x; 1.0061x over previous
//
#include <hip/hip_runtime.h>
#include <math.h>

#define EPSV 1e-5f

typedef __attribute__((ext_vector_type(8)))  short short8_t;
typedef __attribute__((ext_vector_type(4)))  unsigned uint4_t;
typedef __attribute__((ext_vector_type(16))) float f32x16;

static __device__ __forceinline__ short f2bf(float f) {
    union { float f; unsigned u; } v; v.f = f;
    unsigned r = (v.u + 0x7FFFu + ((v.u >> 16) & 1u)) >> 16;
    return (short)r;
}
static __device__ __forceinline__ unsigned pack2bf(float a, float b) {
    return (unsigned)(unsigned short)f2bf(a) | ((unsigned)(unsigned short)f2bf(b) << 16);
}
static __device__ __forceinline__ float bflo(unsigned u) {
    union { unsigned u; float f; } t; t.u = u << 16; return t.f;
}
static __device__ __forceinline__ float bfhi(unsigned u) {
    union { unsigned u; float f; } t; t.u = u & 0xffff0000u; return t.f;
}

// ---------------- prep_all: A2 | A1 | Aup | k0-transpose in ONE launch -----------
// Blocks   0..287  : w_reg -> A2
// Blocks 288..323  : w_off/w_mod -> A1
// Blocks 324..835  : w_up -> Aup
// Blocks 836..2883 : x NCHW -> xT NHWC
// All four are mutually independent (read inputs only, write disjoint ws) -->
// merging removes 3 launch/drain gaps and hides the tiny preps inside k0.
__global__ __launch_bounds__(256) void prep_all(
    const float* __restrict__ w_reg, const float* __restrict__ w_off,
    const float* __restrict__ w_mod, const float* __restrict__ w_up,
    const float* __restrict__ x,
    short* __restrict__ A2, short* __restrict__ A1, short* __restrict__ Aup,
    unsigned short* __restrict__ xT) {
    __shared__ unsigned short t[64 * 65];
    int bx  = blockIdx.x;
    int tid = threadIdx.x;

    if (bx < 288) {                       // ---- A2 ----
        int gid = bx * 256 + tid;
        int l  = gid & 63;
        int ot = (gid >> 6) & 7;
        int s  = gid >> 9;
        int o  = ot * 32 + (l & 31);
        int tap = s >> 4;
        int cb  = (s & 15) * 16 + (l >> 5) * 8;
        short* dst = A2 + (size_t)gid * 8;
#pragma unroll
        for (int j = 0; j < 8; ++j)
            dst[j] = f2bf(w_reg[(o * 256 + cb + j) * 9 + tap]);
    } else if (bx < 324) {                // ---- A1 ----
        int gid = (bx - 288) * 256 + tid;
        int l  = gid & 63;
        int s  = gid >> 6;
        int tap = s >> 4;
        int cq  = s & 15;
        int co  = l & 31;
        int cb  = cq * 16 + (l >> 5) * 8;
        short* dst = A1 + (size_t)gid * 8;
#pragma unroll
        for (int j = 0; j < 8; ++j) {
            int c = cb + j;
            float v = 0.f;
            if (co < 18)      v = w_off[(co * 256 + c) * 9 + tap];
            else if (co < 27) v = w_mod[((co - 18) * 256 + c) * 9 + tap];
            dst[j] = f2bf(v);
        }
    } else if (bx < 836) {                // ---- Aup ----
        int gid = (bx - 324) * 256 + tid;
        int l  = gid & 63;
        int ot = (gid >> 6) & 7;
        int s  = (gid >> 9) & 63;
        int sx = (gid >> 15) & 1;
        int sy = (gid >> 16) & 1;
        int chunk = s >> 4;
        int tap = (s >> 2) & 3;
        int ch  = s & 3;
        int ty = tap >> 1, tx = tap & 1;
        int o  = ot * 32 + (l & 31);
        int cb = chunk * 64 + ch * 16 + (l >> 5) * 8;
        int ky = (1 - sy) + 2 * ty;
        int kx = (1 - sx) + 2 * tx;
        short* dst = Aup + (size_t)gid * 8;
#pragma unroll
        for (int j = 0; j < 8; ++j)
            dst[j] = f2bf(w_up[((cb + j) * 256 + o) * 16 + ky * 4 + kx]);
    } else {                              // ---- k0 transpose ----
        int kb  = bx - 836;
        int b   = kb & 7;
        int hwt = (kb >> 3) & 63;
        int ct  = kb >> 9;
        int g   = tid >> 6;
        int l   = tid & 63;
        const float* xb = x + ((size_t)b * 256 + ct * 64) * 4096 + hwt * 64;
#pragma unroll
        for (int i = 0; i < 16; ++i) {
            int c_l = g * 16 + i;
            t[c_l * 65 + l] = (unsigned short)f2bf(xb[(size_t)c_l * 4096 + l]);
        }
        __syncthreads();
        unsigned short* xo = xT + ((size_t)b * 4096 + hwt * 64) * 256 + ct * 64;
#pragma unroll
        for (int i = 0; i < 16; ++i) {
            int hw_l = g * 16 + i;
            xo[(size_t)hw_l * 256 + l] = t[l * 65 + hw_l];
        }
    }
}

// ---------------- k1: offset+mask conv via bf16 MFMA -> offmask (round-9 exact) --
__global__ __launch_bounds__(256, 2) void k1_mfma(
    const unsigned short* __restrict__ xT, const short* __restrict__ A1,
    const float* __restrict__ b_off, const float* __restrict__ b_mod,
    float* __restrict__ offmask) {
    __shared__ short xs[3 * 66 * 72];     // 28,512 B
    __shared__ float red[4][32][64];      // 32,768 B

    int bx = blockIdx.x;
    int b  = bx & 7;
    int h  = bx >> 3;
    int tid  = threadIdx.x;
    int lane = tid & 63;
    int wv   = tid >> 6;       // 0..3 (K-split)
    int ln = lane & 31;
    int lh = lane >> 5;

    if (tid < 192) {
        int r    = tid >> 6;
        int rest = tid & 63;
        int colp = (rest >> 5) * 65;
        int cd   = rest & 31;
        ((unsigned*)xs)[((r * 66 + colp) * 72 >> 1) + cd] = 0;
    }

    f32x16 acc[2];
#pragma unroll
    for (int pt = 0; pt < 2; ++pt)
#pragma unroll
        for (int r = 0; r < 16; ++r) acc[pt][r] = 0.f;

    const unsigned short* xTb = xT + (size_t)b * 4096 * 256;

    for (int cc = 0; cc < 256; cc += 64) {
#pragma unroll
        for (int it = 0; it < 6; ++it) {
            int e   = tid + it * 256;
            int ch8 = e & 7;             // 8-c chunk
            int col = (e >> 3) & 63;
            int r   = e >> 9;            // 0..2
            int row = h - 1 + r;
            bool v  = (row >= 0) & (row <= 63);
            short8_t val = {0,0,0,0,0,0,0,0};
            if (v) val = *(const short8_t*)(xTb + ((size_t)row * 64 + col) * 256 + cc + ch8 * 8);
            *(short8_t*)&xs[(r * 66 + col + 1) * 72 + ch8 * 8] = val;
        }
        __syncthreads();

#pragma unroll
        for (int tap = 0; tap < 9; ++tap) {
            int ky = tap / 3, kx = tap - 3 * (tap / 3);
            int s = tap * 16 + (cc >> 4) + wv;
            short8_t afr = *(const short8_t*)(A1 + ((size_t)s * 64 + lane) * 8);
            const short* bp = &xs[(ky * 66 + ln + kx) * 72 + wv * 16 + lh * 8];
            short8_t b0 = *(const short8_t*)bp;
            short8_t b1 = *(const short8_t*)(bp + 32 * 72);
            acc[0] = __builtin_amdgcn_mfma_f32_32x32x16_bf16(afr, b0, acc[0], 0, 0, 0);
            acc[1] = __builtin_amdgcn_mfma_f32_32x32x16_bf16(afr, b1, acc[1], 0, 0, 0);
        }
        __syncthreads();
    }

#pragma unroll
    for (int pt = 0; pt < 2; ++pt)
#pragma unroll
        for (int reg = 0; reg < 16; ++reg) {
            int row = (reg & 3) + 8 * (reg >> 2) + 4 * lh;
            red[wv][row][pt * 32 + ln] = acc[pt][reg];
        }
    __syncthreads();

    int pos = tid & 63;
    int cg  = tid >> 6;
#pragma unroll
    for (int i = 0; i < 7; ++i) {
        int co = 4 * i + cg;
        if (co < 27) {
            float sum = red[0][co][pos] + red[1][co][pos]
                      + red[2][co][pos] + red[3][co][pos];
            if (co < 18) {
                sum += b_off[co];
            } else {
                sum += b_mod[co - 18];
                sum = 2.f / (1.f + expf(-sum));
            }
            offmask[((size_t)(b * 27 + co) << 12) + (h << 6) + pos] = sum;
        }
    }
}

// ---------------- k2: deform sample (dwordx4 gather) + MFMA + bn1+relu -> h1 -----
// Round-9 version EXACTLY (best verified).
__global__ __launch_bounds__(512, 4) void k2_deform(
    const unsigned short* __restrict__ xT, const float* __restrict__ offmask,
    const short* __restrict__ A2,
    const float* __restrict__ g1, const float* __restrict__ be1,
    const float* __restrict__ mu1, const float* __restrict__ va1,
    unsigned short* __restrict__ h1) {
    __shared__ unsigned short lds_v[64 * 264];   // [pos][c], pitch 264
    __shared__ int   sidx[9][64][4];
    __shared__ float swt [9][64][4];

    int bx = blockIdx.x;
    int b  = bx & 7;
    int h  = bx >> 3;
    int tid  = threadIdx.x;
    int lane = tid & 63;
    int wv   = tid >> 6;          // 0..7
    int ln = lane & 31;
    int lh = lane >> 5;

#pragma unroll
    for (int it = 0; it < 2; ++it) {
        int e = it * 512 + tid;
        if (e < 576) {
            int tap = e >> 6;
            int pos = e & 63;
            const float* om = offmask + ((size_t)b * 27 << 12) + (h << 6) + pos;
            float oy = om[(size_t)(2 * tap) << 12];
            float ox = om[(size_t)(2 * tap + 1) << 12];
            float m2 = om[(size_t)(18 + tap) << 12];
            int ky = tap / 3, kx = tap - 3 * (tap / 3);
            float py = (float)(h - 1 + ky) + oy;
            float px = (float)(pos - 1 + kx) + ox;
            float y0f = floorf(py), x0f = floorf(px);
            float wy1 = py - y0f, wy0 = 1.f - wy1;
            float wx1 = px - x0f, wx0 = 1.f - wx1;
            int y0 = (int)y0f, xq = (int)x0f;
            int y1 = y0 + 1, x1 = xq + 1;
            bool vy0 = (y0 >= 0) & (y0 < 64), vy1 = (y1 >= 0) & (y1 < 64);
            bool vx0 = (xq >= 0) & (xq < 64), vx1 = (x1 >= 0) & (x1 < 64);
            int y0c = min(max(y0, 0), 63), y1c = min(max(y1, 0), 63);
            int x0c = min(max(xq, 0), 63), x1c = min(max(x1, 0), 63);
            sidx[tap][pos][0] = y0c * 64 + x0c;  swt[tap][pos][0] = (vy0 && vx0) ? m2 * wy0 * wx0 : 0.f;
            sidx[tap][pos][1] = y0c * 64 + x1c;  swt[tap][pos][1] = (vy0 && vx1) ? m2 * wy0 * wx1 : 0.f;
            sidx[tap][pos][2] = y1c * 64 + x0c;  swt[tap][pos][2] = (vy1 && vx0) ? m2 * wy1 * wx0 : 0.f;
            sidx[tap][pos][3] = y1c * 64 + x1c;  swt[tap][pos][3] = (vy1 && vx1) ? m2 * wy1 * wx1 : 0.f;
        }
    }
    __syncthreads();

    f32x16 acc[2];
#pragma unroll
    for (int pt = 0; pt < 2; ++pt)
#pragma unroll
        for (int r = 0; r < 16; ++r) acc[pt][r] = 0.f;

    const unsigned* xTb = (const unsigned*)(xT + (size_t)b * 4096 * 256);

    for (int k = 0; k < 9; ++k) {
#pragma unroll
        for (int qq = 0; qq < 4; ++qq) {
            int pos = wv * 8 + qq * 2 + lh;      // lanes 0-31: even pos, 32-63: odd
            float a[8];
#pragma unroll
            for (int j = 0; j < 8; ++j) a[j] = 0.f;
#pragma unroll
            for (int i = 0; i < 4; ++i) {
                int   idx = sidx[k][pos][i];
                float wt  = swt[k][pos][i];
                uint4_t u = *(const uint4_t*)(xTb + ((size_t)idx << 7) + (ln << 2));
#pragma unroll
                for (int d = 0; d < 4; ++d) {
                    a[2 * d + 0] = fmaf(wt, bflo(u[d]), a[2 * d + 0]);
                    a[2 * d + 1] = fmaf(wt, bfhi(u[d]), a[2 * d + 1]);
                }
            }
            unsigned* dst = (unsigned*)&lds_v[pos * 264 + ln * 8];
            uint4_t w;
            w[0] = pack2bf(a[0], a[1]);
            w[1] = pack2bf(a[2], a[3]);
            w[2] = pack2bf(a[4], a[5]);
            w[3] = pack2bf(a[6], a[7]);
            *(uint4_t*)dst = w;
        }
        __syncthreads();

#pragma unroll 4
        for (int sl = 0; sl < 16; ++sl) {
            int s = k * 16 + sl;
            short8_t afr = *(const short8_t*)(A2 + (((size_t)s * 8 + wv) * 64 + lane) * 8);
            short8_t b0 = *(const short8_t*)&lds_v[ln        * 264 + sl * 16 + lh * 8];
            short8_t b1 = *(const short8_t*)&lds_v[(32 + ln) * 264 + sl * 16 + lh * 8];
            acc[0] = __builtin_amdgcn_mfma_f32_32x32x16_bf16(afr, b0, acc[0], 0, 0, 0);
            acc[1] = __builtin_amdgcn_mfma_f32_32x32x16_bf16(afr, b1, acc[1], 0, 0, 0);
        }
        __syncthreads();
    }

#pragma unroll
    for (int reg = 0; reg < 16; ++reg) {
        int o = wv * 32 + (reg & 3) + 8 * (reg >> 2) + 4 * lh;
        float sc = g1[o] / sqrtf(va1[o] + EPSV);
        float sh = be1[o] - mu1[o] * sc;
        size_t ob = ((size_t)(b * 256 + o) * 64 + h) * 64;
#pragma unroll
        for (int pt = 0; pt < 2; ++pt) {
            float v = fmaxf(fmaf(acc[pt][reg], sc, sh), 0.f);
            h1[ob + pt * 32 + ln] = (unsigned short)f2bf(v);
        }
    }
}

// ---------------- k3: conv_transpose via bf16 MFMA, 256-thr o-split (round 8) ----
__global__ __launch_bounds__(256, 4) void k3_convt(
    const unsigned short* __restrict__ h1, const short* __restrict__ Aup,
    const float* __restrict__ g2, const float* __restrict__ be2,
    const float* __restrict__ mu2, const float* __restrict__ va2,
    float* __restrict__ out) {
    __shared__ short lds[2 * 66 * 72];   // 19,008 B

    int bx = blockIdx.x;
    int oh = bx & 1;             // o-half
    int b  = (bx >> 1) & 7;
    int y  = bx >> 4;            // 0..127
    int sy = y & 1;
    int m  = y >> 1;
    int tid  = threadIdx.x;      // 0..255
    int lane = tid & 63;
    int wv   = tid >> 6;         // 0..3
    int owh = wv & 1;
    int sx  = wv >> 1;
    int ln = lane & 31;
    int lh = lane >> 5;

    int row0 = m + sy;           // ty=0 source row
    int row1 = row0 - 1;         // ty=1 source row
    bool v0 = (row0 <= 63);
    bool v1 = (row1 >= 0);

#pragma unroll
    for (int e0 = 0; e0 < 2; ++e0) {
        int e = tid + e0 * 256;
        if (e < 288) {
            int r  = e / 144;
            int rm = e - r * 144;
            int cp = (rm / 72) * 65;
            int cz = rm - (rm / 72) * 72;
            lds[(r * 66 + cp) * 72 + cz] = 0;
        }
    }

    f32x16 acc[2][2];            // [i o-tile][mh]
#pragma unroll
    for (int i = 0; i < 2; ++i)
#pragma unroll
        for (int mh = 0; mh < 2; ++mh)
#pragma unroll
            for (int r = 0; r < 16; ++r) acc[i][mh][r] = 0.f;

    const unsigned short* hb = h1 + (size_t)b * 256 * 4096;
    const short* Abase = Aup + (size_t)(sy * 2 + sx) * 262144;
    int col = tid & 63;
    int ug  = tid >> 6;          // 0..3 staging group

    for (int cc = 0; cc < 256; cc += 64) {
#pragma unroll
        for (int it = 0; it < 8; ++it) {
            int idx  = ug + 4 * it;      // 0..31
            int r    = idx >> 4;
            int quad = idx & 15;
            int row  = r ? row1 : row0;
            bool v   = r ? v1 : v0;
            int cb   = cc + quad * 4;
            unsigned short u0 = v ? hb[(size_t)(cb + 0) * 4096 + row * 64 + col] : 0;
            unsigned short u1 = v ? hb[(size_t)(cb + 1) * 4096 + row * 64 + col] : 0;
            unsigned short u2 = v ? hb[(size_t)(cb + 2) * 4096 + row * 64 + col] : 0;
            unsigned short u3 = v ? hb[(size_t)(cb + 3) * 4096 + row * 64 + col] : 0;
            unsigned* dst = (unsigned*)&lds[(r * 66 + col + 1) * 72 + quad * 4];
            dst[0] = (unsigned)u0 | ((unsigned)u1 << 16);
            dst[1] = (unsigned)u2 | ((unsigned)u3 << 16);
        }
        __syncthreads();

#pragma unroll
        for (int st = 0; st < 16; ++st) {
            int tap = st >> 2;
            int ch  = st & 3;
            int ty = tap >> 1, tx = tap & 1;
            int s_g = (cc >> 2) + st;
            const short* ap = Abase + (size_t)s_g * 4096 + lane * 8;
            short8_t a0 = *(const short8_t*)(ap + (size_t)(oh * 4 + owh) * 512);
            short8_t a1 = *(const short8_t*)(ap + (size_t)(oh * 4 + owh + 2) * 512);
            int cbase = ty * 66 + ln + sx - tx + 1;
            short8_t b0 = *(const short8_t*)&lds[cbase * 72 + ch * 16 + lh * 8];
            short8_t b1 = *(const short8_t*)&lds[(cbase + 32) * 72 + ch * 16 + lh * 8];
            acc[0][0] = __builtin_amdgcn_mfma_f32_32x32x16_bf16(a0, b0, acc[0][0], 0, 0, 0);
            acc[0][1] = __builtin_amdgcn_mfma_f32_32x32x16_bf16(a0, b1, acc[0][1], 0, 0, 0);
            acc[1][0] = __builtin_amdgcn_mfma_f32_32x32x16_bf16(a1, b0, acc[1][0], 0, 0, 0);
            acc[1][1] = __builtin_amdgcn_mfma_f32_32x32x16_bf16(a1, b1, acc[1][1], 0, 0, 0);
        }
        __syncthreads();
    }

#pragma unroll
    for (int i = 0; i < 2; ++i) {
#pragma unroll
        for (int reg = 0; reg < 16; ++reg) {
            int o = (oh * 4 + owh + 2 * i) * 32 + (reg & 3) + 8 * (reg >> 2) + 4 * lh;
            float sc = g2[o] / sqrtf(va2[o] + EPSV);
            float sh = be2[o] - mu2[o] * sc;
            size_t ob = ((size_t)(b * 256 + o) * 128 + y) * 128;
#pragma unroll
            for (int mh = 0; mh < 2; ++mh) {
                int x = 2 * (mh * 32 + ln) + sx;
                out[ob + x] = fmaxf(fmaf(acc[i][mh][reg], sc, sh), 0.f);
            }
        }
    }
}

extern "C" void kernel_launch(void* const* d_in, const int* in_sizes, int n_in,
                              void* d_out, int out_size, void* d_ws, size_t ws_size,
                              hipStream_t stream) {
    const float* x      = (const float*)d_in[0];
    const float* w_off  = (const float*)d_in[1];
    const float* b_off  = (const float*)d_in[2];
    const float* w_mod  = (const float*)d_in[3];
    const float* b_mod  = (const float*)d_in[4];
    const float* w_reg  = (const float*)d_in[5];
    const float* g1     = (const float*)d_in[6];
    const float* be1    = (const float*)d_in[7];
    const float* mu1    = (const float*)d_in[8];
    const float* va1    = (const float*)d_in[9];
    const float* w_up   = (const float*)d_in[10];
    const float* g2     = (const float*)d_in[11];
    const float* be2    = (const float*)d_in[12];
    const float* mu2    = (const float*)d_in[13];
    const float* va2    = (const float*)d_in[14];

    float* ws      = (float*)d_ws;
    float* offmask = ws;                                     //   884,736 f
    short* A2      = (short*)(offmask + 884736);             //   589,824 sh
    short* A1      = A2 + 589824;                            //    73,728 sh
    short* Aup     = A1 + 73728;                             // 1,048,576 sh
    unsigned short* h1 = (unsigned short*)(Aup + 1048576);   // 8,388,608 sh
    unsigned short* xT = h1 + 8388608;                       // 8,388,608 sh

    prep_all  <<<2884, 256, 0, stream>>>(w_reg, w_off, w_mod, w_up, x,
                                         A2, A1, Aup, xT);
    k1_mfma   <<<512,  256, 0, stream>>>(xT, A1, b_off, b_mod, offmask);
    k2_deform <<<512,  512, 0, stream>>>(xT, offmask, A2, g1, be1, mu1, va1, h1);
    k3_convt  <<<2048, 256, 0, stream>>>(h1, Aup, g2, be2, mu2, va2, (float*)d_out);
}